// Round 10
// baseline (190.409 us; speedup 1.0000x reference)
//
#include <hip/hip_runtime.h>

namespace {

typedef float  f32x2  __attribute__((ext_vector_type(2)));
typedef float  f32x4  __attribute__((ext_vector_type(4)));
typedef short  bf16x8 __attribute__((ext_vector_type(8)));
typedef unsigned short u16;

constexpr int S   = 32;    // neighbors
constexpr int F   = 128;   // features
constexpr int TPB = 256;   // 4 waves

// ---- Batcher odd-even mergesort network for 16 elements (63 CEs) ----
struct CEPair { int a, b; };

constexpr int batcher_count16() {
  int n = 16, cnt = 0;
  for (int p = 1; p < n; p <<= 1)
    for (int k = p; k >= 1; k >>= 1)
      for (int j = k % p; j + k < n; j += 2 * k)
        for (int i = 0; i < k && i + j + k < n; ++i)
          if ((i + j) / (2 * p) == (i + j + k) / (2 * p))
            ++cnt;
  return cnt;
}
constexpr int NCE = batcher_count16();   // 63

struct Net16 { CEPair ce[NCE]; };

constexpr Net16 make_net16() {
  Net16 net{};
  int n = 16, c = 0;
  for (int p = 1; p < n; p <<= 1)
    for (int k = p; k >= 1; k >>= 1)
      for (int j = k % p; j + k < n; j += 2 * k)
        for (int i = 0; i < k && i + j + k < n; ++i)
          if ((i + j) / (2 * p) == (i + j + k) / (2 * p))
            net.ce[c++] = CEPair{i + j, i + j + k};
  return net;
}
constexpr Net16 NET16 = make_net16();

__device__ __forceinline__ f32x2 min2(f32x2 a, f32x2 b) {
  f32x2 r; r.x = fminf(a.x, b.x); r.y = fminf(a.y, b.y); return r;
}
__device__ __forceinline__ f32x2 max2(f32x2 a, f32x2 b) {
  f32x2 r; r.x = fmaxf(a.x, b.x); r.y = fmaxf(a.y, b.y); return r;
}

template<int T>
__device__ __forceinline__ void sort16(f32x2 (&v)[16]) {
  if constexpr (T < NCE) {
    constexpr int a = NET16.ce[T].a;
    constexpr int b = NET16.ce[T].b;
    f32x2 x = v[a], y = v[b];
    v[a] = min2(x, y);
    v[b] = max2(x, y);
    sort16<T + 1>(v);
  }
}

// fp32 -> bf16 round-to-nearest-even
__device__ __forceinline__ unsigned f2bf(float f) {
  unsigned u = __builtin_bit_cast(unsigned, f);
  return (u + 0x7FFFu + ((u >> 16) & 1u)) >> 16;
}

__device__ __forceinline__ void issue_row_k1(const float* __restrict__ neigh,
                                             int row, int lane,
                                             f32x2 (&A)[16], f32x2 (&B)[16])
{
    const f32x2* nb = (const f32x2*)(neigh + (size_t)row * (S * F)) + lane;
#pragma unroll
    for (int s = 0; s < 16; ++s)
        A[s] = __builtin_nontemporal_load(nb + (size_t)s * 64);
#pragma unroll
    for (int s = 0; s < 16; ++s)
        B[s] = __builtin_nontemporal_load(nb + (size_t)(s + 16) * 64);
}

// rank-16-of-32 (0-indexed): min_{i=1..16} max(A[i-1], B[16-i]); store bf16x2
__device__ __forceinline__ void select_store_med(f32x2 (&A)[16], f32x2 (&B)[16],
                                                 unsigned* __restrict__ dst)
{
    sort16<0>(A);
    sort16<0>(B);
#pragma unroll
    for (int q = 0; q < 16; ++q) A[q] = max2(A[q], B[15 - q]);
#pragma unroll
    for (int st = 8; st >= 1; st >>= 1)
#pragma unroll
        for (int q = 0; q < st; ++q) A[q] = min2(A[q], A[q + st]);
    __builtin_nontemporal_store(f2bf(A[0].x) | (f2bf(A[0].y) << 16), dst);
}

// ============ Kernel 1: pure median stream (no x, no LDS, no GEMM) ============
// R5's proven ping-pong: row r+1's 32 loads outstanding while row r sorts.
__global__ __launch_bounds__(TPB, 3) void median_pass(
    const float* __restrict__ neigh,
    unsigned* __restrict__ med,      // [N][64] packed bf16 pairs
    int N)
{
    const int tid  = threadIdx.x;
    const int wv   = tid >> 6;
    const int lane = tid & 63;
    const int row0 = blockIdx.x * 32 + wv * 8;
    const int rmax = N - 1;
    auto rw = [&](int rl) { int r = row0 + rl; return r > rmax ? rmax : r; };

    f32x2 A0[16], B0[16], A1[16], B1[16];

    issue_row_k1(neigh, rw(0), lane, A0, B0);
#pragma unroll
    for (int p = 0; p < 4; ++p) {
        issue_row_k1(neigh, rw(2 * p + 1), lane, A1, B1);
        select_store_med(A0, B0, &med[(size_t)rw(2 * p) * 64 + lane]);
        if (p < 3)
            issue_row_k1(neigh, rw(2 * p + 2), lane, A0, B0);
        select_store_med(A1, B1, &med[(size_t)rw(2 * p + 1) * 64 + lane]);
    }
}

// ============ weight fragment pre-kernel (R8, validated) ============
// Chunk (c,kk): lane l holds W[kk*32+(l>>4)*8+j][c*16+(l&15)] as 8 bf16.
__global__ void convert_weights(const float* __restrict__ Ks,
                                const float* __restrict__ Kn,
                                u16* __restrict__ wsb)
{
    const int t  = blockIdx.x * 256 + threadIdx.x;   // 0..4095
    const int c  = t >> 8;
    const int kk = (t >> 6) & 3;
    const int l  = t & 63;
    const int n  = c * 16 + (l & 15);
    const int kb = kk * 32 + (l >> 4) * 8;
    const float* __restrict__ W = (n < 128) ? Ks : Kn;
    const int nn = n & 127;

    u16 tmp[8];
#pragma unroll
    for (int j = 0; j < 8; ++j)
        tmp[j] = (u16)f2bf(W[(size_t)(kb + j) * 128 + nn]);

    u16* dst = wsb + (size_t)(c * 4 + kk) * 512 + (size_t)l * 8;
#pragma unroll
    for (int j = 0; j < 8; ++j) dst[j] = tmp[j];
}

// ============ Kernel 2: standalone dual GEMM on the matrix pipe ============
// D^T trick: mfma(weights_frag, rows_frag) computes out^T, whose lane layout
// gives each lane 4 CONSECUTIVE output cols of one row -> f32x4 NT stores.
// Wave = 16 rows. A/B 16x16x32 fragment layouts: idx = lane&15, k=(lane>>4)*8+j.
__global__ __launch_bounds__(TPB, 4) void gemm_pass(
    const float* __restrict__ x,
    const u16*   __restrict__ med,     // [N][128] bf16
    const u16*   __restrict__ wfrag,
    const float* __restrict__ bias,
    float* __restrict__ out,
    int N)
{
    const int tid  = threadIdx.x;
    const int wv   = tid >> 6;
    const int lane = tid & 63;
    const int rsel = lane & 15;                    // row within wave tile
    const int ag   = lane >> 4;                    // 0..3 (k-group / col-group)
    const int rmax = N - 1;

    int row = blockIdx.x * 64 + wv * 16 + rsel;
    if (row > rmax) row = rmax;                    // dup rows -> identical output

    bf16x8 ax[4], am[4];
#pragma unroll
    for (int kk = 0; kk < 4; ++kk) {
        const int kb = kk * 32 + ag * 8;
        // x: 8 fp32 -> bf16x8
        const f32x4 u0 = *(const f32x4*)&x[(size_t)row * F + kb];
        const f32x4 u1 = *(const f32x4*)&x[(size_t)row * F + kb + 4];
        bf16x8 v;
        v[0] = (short)f2bf(u0.x); v[1] = (short)f2bf(u0.y);
        v[2] = (short)f2bf(u0.z); v[3] = (short)f2bf(u0.w);
        v[4] = (short)f2bf(u1.x); v[5] = (short)f2bf(u1.y);
        v[6] = (short)f2bf(u1.z); v[7] = (short)f2bf(u1.w);
        ax[kk] = v;
        // med: direct 16B bf16 load
        am[kk] = *(const bf16x8*)&med[(size_t)row * F + kb];
    }

    const bf16x8* __restrict__ wsf = (const bf16x8*)wfrag;

#pragma unroll 4
    for (int c = 0; c < 16; ++c) {
        f32x4 acc = f32x4{0.f, 0.f, 0.f, 0.f};
#pragma unroll
        for (int kk = 0; kk < 4; ++kk) {
            const bf16x8 b = wsf[(c * 4 + kk) * 64 + lane];
            acc = __builtin_amdgcn_mfma_f32_16x16x32_bf16(
                      b, (c < 8) ? ax[kk] : am[kk], acc, 0, 0, 0);
        }
        const int col = c * 16 + ag * 4;           // 4 consecutive cols
        const f32x4 bv = *(const f32x4*)&bias[col];
        f32x4 o;
        o.x = fmaxf(acc.x + bv.x, 0.f);
        o.y = fmaxf(acc.y + bv.y, 0.f);
        o.z = fmaxf(acc.z + bv.z, 0.f);
        o.w = fmaxf(acc.w + bv.w, 0.f);
        __builtin_nontemporal_store(o, (f32x4*)&out[(size_t)row * 256 + col]);
    }
}

// ============ Fallback: R9 fused kernel (used only if ws too small) ============
template<int T>
__device__ __forceinline__ void sort16s(float (&v)[16]) {
  if constexpr (T < NCE) {
    constexpr int a = NET16.ce[T].a;
    constexpr int b = NET16.ce[T].b;
    float x = v[a], y = v[b];
    v[a] = fminf(x, y);
    v[b] = fmaxf(x, y);
    sort16s<T + 1>(v);
  }
}

__device__ __forceinline__ void issue_half(const float* __restrict__ neigh,
                                           const float* __restrict__ x,
                                           int row, int h, int lane,
                                           float (&A)[16], float (&B)[16],
                                           float& xv)
{
    const float* nb = neigh + (size_t)row * (S * F) + h * 64 + lane;
#pragma unroll
    for (int s = 0; s < 16; ++s)
        A[s] = __builtin_nontemporal_load(nb + s * F);
#pragma unroll
    for (int s = 0; s < 16; ++s)
        B[s] = __builtin_nontemporal_load(nb + (s + 16) * F);
    xv = x[(size_t)row * F + h * 64 + lane];
}

__device__ __forceinline__ void select_store(float (&A)[16], float (&B)[16],
                                             float xv,
                                             float* __restrict__ msrow,
                                             float* __restrict__ xsrow,
                                             int h, int lane)
{
    sort16s<0>(A);
    sort16s<0>(B);
#pragma unroll
    for (int q = 0; q < 16; ++q) A[q] = fmaxf(A[q], B[15 - q]);
#pragma unroll
    for (int st = 8; st >= 1; st >>= 1)
#pragma unroll
        for (int q = 0; q < st; ++q) A[q] = fminf(A[q], A[q + st]);
    msrow[h * 64 + lane] = A[0];
    xsrow[h * 64 + lane] = xv;
}

__global__ __launch_bounds__(TPB, 3) void fused_median_gemm(
    const float* __restrict__ x,
    const float* __restrict__ neigh,
    const float* __restrict__ Ks,
    const float* __restrict__ Kn,
    const float* __restrict__ bias,
    float* __restrict__ out,
    int N)
{
    __shared__ __align__(16) float xs[4][8][F];
    __shared__ __align__(16) float ms[4][8][F];

    const int tid  = threadIdx.x;
    const int wv   = tid >> 6;
    const int lane = tid & 63;
    const int row0 = blockIdx.x * 32 + wv * 8;
    const int rmax = N - 1;
    auto rw = [&](int hp) { int r = row0 + (hp >> 1); return r > rmax ? rmax : r; };

    {
        float A0[16], B0[16], A1[16], B1[16];
        float A2[16], B2[16], A3[16], B3[16];
        float x0, x1, x2, x3;

        issue_half(neigh, x, rw(0), 0, lane, A0, B0, x0);
        issue_half(neigh, x, rw(1), 1, lane, A1, B1, x1);
        issue_half(neigh, x, rw(2), 0, lane, A2, B2, x2);

#pragma unroll 1
        for (int q = 0; q < 4; ++q) {
            const int hp = q * 4;
            issue_half(neigh, x, rw(hp + 3), (hp + 3) & 1, lane, A3, B3, x3);
            select_store(A0, B0, x0, &ms[wv][hp >> 1][0], &xs[wv][hp >> 1][0],
                         hp & 1, lane);
            if (hp + 4 < 16)
                issue_half(neigh, x, rw(hp + 4), (hp + 4) & 1, lane, A0, B0, x0);
            select_store(A1, B1, x1, &ms[wv][(hp + 1) >> 1][0], &xs[wv][(hp + 1) >> 1][0],
                         (hp + 1) & 1, lane);
            if (hp + 5 < 16)
                issue_half(neigh, x, rw(hp + 5), (hp + 5) & 1, lane, A1, B1, x1);
            select_store(A2, B2, x2, &ms[wv][(hp + 2) >> 1][0], &xs[wv][(hp + 2) >> 1][0],
                         (hp + 2) & 1, lane);
            if (hp + 6 < 16)
                issue_half(neigh, x, rw(hp + 6), (hp + 6) & 1, lane, A2, B2, x2);
            select_store(A3, B3, x3, &ms[wv][(hp + 3) >> 1][0], &xs[wv][(hp + 3) >> 1][0],
                         (hp + 3) & 1, lane);
        }
    }

    asm volatile("s_waitcnt lgkmcnt(0)" ::: "memory");

    const bool self_half = (lane < 32);
    const float* __restrict__ W = self_half ? Ks : Kn;
    const int wcol = (lane * 4) & 127;
    const float* lin = self_half ? &xs[wv][0][0] : &ms[wv][0][0];

    f32x4 acc[8];
#pragma unroll
    for (int r = 0; r < 8; ++r) acc[r] = f32x4{0.f, 0.f, 0.f, 0.f};

#pragma unroll 4
    for (int k4 = 0; k4 < 32; ++k4) {
        f32x4 wv4[4];
#pragma unroll
        for (int dk = 0; dk < 4; ++dk)
            wv4[dk] = *(const f32x4*)&W[(k4 * 4 + dk) * 128 + wcol];
        f32x4 xr[8];
#pragma unroll
        for (int r = 0; r < 8; ++r)
            xr[r] = *(const f32x4*)&lin[r * F + k4 * 4];
#pragma unroll
        for (int r = 0; r < 8; ++r) {
#pragma unroll
            for (int dk = 0; dk < 4; ++dk) {
                const float s = xr[r][dk];
                acc[r].x = fmaf(s, wv4[dk].x, acc[r].x);
                acc[r].y = fmaf(s, wv4[dk].y, acc[r].y);
                acc[r].z = fmaf(s, wv4[dk].z, acc[r].z);
                acc[r].w = fmaf(s, wv4[dk].w, acc[r].w);
            }
        }
    }

    const f32x4 bv = *(const f32x4*)&bias[lane * 4];
#pragma unroll
    for (int r = 0; r < 8; ++r) {
        int row = row0 + r;
        if (row > rmax) row = rmax;
        f32x4 o;
        o.x = fmaxf(acc[r].x + bv.x, 0.f);
        o.y = fmaxf(acc[r].y + bv.y, 0.f);
        o.z = fmaxf(acc[r].z + bv.z, 0.f);
        o.w = fmaxf(acc[r].w + bv.w, 0.f);
        __builtin_nontemporal_store(o, (f32x4*)&out[(size_t)row * 256 + lane * 4]);
    }
}

} // namespace

extern "C" void kernel_launch(void* const* d_in, const int* in_sizes, int n_in,
                              void* d_out, int out_size, void* d_ws, size_t ws_size,
                              hipStream_t stream) {
    const float* x     = (const float*)d_in[0];
    const float* neigh = (const float*)d_in[1];
    const float* Ks    = (const float*)d_in[2];
    const float* Kn    = (const float*)d_in[3];
    const float* bias  = (const float*)d_in[4];
    float* out = (float*)d_out;

    const int N = in_sizes[0] / F;   // 50000
    const size_t med_bytes = (size_t)N * 64 * sizeof(unsigned);   // 12.8 MB
    const size_t need = med_bytes + 16 * 4 * 512 * sizeof(u16);   // + 64 KB frags

    if (ws_size >= need) {
        unsigned* med = (unsigned*)d_ws;
        u16* wsb = (u16*)((char*)d_ws + med_bytes);

        hipLaunchKernelGGL(convert_weights, dim3(16), dim3(256), 0, stream,
                           Ks, Kn, wsb);
        hipLaunchKernelGGL(median_pass, dim3((N + 31) / 32), dim3(TPB), 0, stream,
                           neigh, med, N);
        hipLaunchKernelGGL(gemm_pass, dim3((N + 63) / 64), dim3(TPB), 0, stream,
                           x, (const u16*)med, wsb, bias, out, N);
    } else {
        hipLaunchKernelGGL(fused_median_gemm, dim3((N + 31) / 32), dim3(TPB), 0,
                           stream, x, neigh, Ks, Kn, bias, out, N);
    }
}

// Round 11
// 182.410 us; speedup vs baseline: 1.0439x; 1.0439x over previous
//
#include <hip/hip_runtime.h>

namespace {

typedef float f32x4 __attribute__((ext_vector_type(4)));

constexpr int S   = 32;    // neighbors
constexpr int F   = 128;   // features
constexpr int BR  = 32;    // rows per block (8 per wave)
constexpr int TPB = 256;   // 4 waves

// ---- Batcher odd-even mergesort network for 16 elements (63 CEs) ----
struct CEPair { int a, b; };

constexpr int batcher_count16() {
  int n = 16, cnt = 0;
  for (int p = 1; p < n; p <<= 1)
    for (int k = p; k >= 1; k >>= 1)
      for (int j = k % p; j + k < n; j += 2 * k)
        for (int i = 0; i < k && i + j + k < n; ++i)
          if ((i + j) / (2 * p) == (i + j + k) / (2 * p))
            ++cnt;
  return cnt;
}
constexpr int NCE = batcher_count16();   // 63

struct Net16 { CEPair ce[NCE]; };

constexpr Net16 make_net16() {
  Net16 net{};
  int n = 16, c = 0;
  for (int p = 1; p < n; p <<= 1)
    for (int k = p; k >= 1; k >>= 1)
      for (int j = k % p; j + k < n; j += 2 * k)
        for (int i = 0; i < k && i + j + k < n; ++i)
          if ((i + j) / (2 * p) == (i + j + k) / (2 * p))
            net.ce[c++] = CEPair{i + j, i + j + k};
  return net;
}
constexpr Net16 NET16 = make_net16();

template<int T>
__device__ __forceinline__ void sort16(float (&v)[16]) {
  if constexpr (T < NCE) {
    constexpr int a = NET16.ce[T].a;
    constexpr int b = NET16.ce[T].b;
    float x = v[a], y = v[b];
    v[a] = fminf(x, y);
    v[b] = fmaxf(x, y);
    sort16<T + 1>(v);
  }
}

// Issue one HALF-row (32 neighbors x 64 features; lane = one feature):
// 32 nontemporal 256B loads + one x element. No waits here — the consumer's
// compiler-counted vmcnt waits only for ITS 33 loads, leaving the other
// slots' loads in flight (up to 3 half-rows = 24 KB lookahead per wave).
__device__ __forceinline__ void issue_half(const float* __restrict__ neigh,
                                           const float* __restrict__ x,
                                           int row, int h, int lane,
                                           float (&A)[16], float (&B)[16],
                                           float& xv)
{
    const float* nb = neigh + (size_t)row * (S * F) + h * 64 + lane;
#pragma unroll
    for (int s = 0; s < 16; ++s)
        A[s] = __builtin_nontemporal_load(nb + s * F);
#pragma unroll
    for (int s = 0; s < 16; ++s)
        B[s] = __builtin_nontemporal_load(nb + (s + 16) * F);
    xv = x[(size_t)row * F + h * 64 + lane];
}

// rank-16 (0-indexed) of 32 = min_{i=1..16} max(A[i-1], B[16-i])
__device__ __forceinline__ void select_store(float (&A)[16], float (&B)[16],
                                             float xv,
                                             float* __restrict__ msrow,
                                             float* __restrict__ xsrow,
                                             int h, int lane)
{
    sort16<0>(A);
    sort16<0>(B);
#pragma unroll
    for (int q = 0; q < 16; ++q) A[q] = fmaxf(A[q], B[15 - q]);
#pragma unroll
    for (int st = 8; st >= 1; st >>= 1)
#pragma unroll
        for (int q = 0; q < st; ++q) A[q] = fminf(A[q], A[q + st]);
    msrow[h * 64 + lane] = A[0];
    xsrow[h * 64 + lane] = xv;
}

// Barrier-free, wave-owned rows. Phase A: 16 half-row chunks in a 4-deep
// slot rotation — 3 chunks (24 KB) always in flight while one sorts.
__global__ __launch_bounds__(TPB, 3) void fused_median_gemm(
    const float* __restrict__ x,
    const float* __restrict__ neigh,
    const float* __restrict__ Ks,
    const float* __restrict__ Kn,
    const float* __restrict__ bias,
    float* __restrict__ out,
    int N)
{
    __shared__ __align__(16) float xs[4][8][F];   // 16 KB
    __shared__ __align__(16) float ms[4][8][F];   // 16 KB

    const int tid  = threadIdx.x;
    const int wv   = tid >> 6;                    // wave id 0..3
    const int lane = tid & 63;                    // feature within half-row
    const int row0 = blockIdx.x * BR + wv * 8;

    const int rmax = N - 1;
    auto rw = [&](int hp) { int r = row0 + (hp >> 1); return r > rmax ? rmax : r; };

    // ---------- Phase A: 4-deep pipelined rank-16-of-32 (16 half-row chunks) ----------
    {
        float A0[16], B0[16], A1[16], B1[16];
        float A2[16], B2[16], A3[16], B3[16];
        float x0, x1, x2, x3;

        issue_half(neigh, x, rw(0), 0, lane, A0, B0, x0);
        issue_half(neigh, x, rw(1), 1, lane, A1, B1, x1);
        issue_half(neigh, x, rw(2), 0, lane, A2, B2, x2);

#pragma unroll 1
        for (int q = 0; q < 4; ++q) {
            const int hp = q * 4;
            // step 0: work slot0, prefetch hp+3 -> slot3
            issue_half(neigh, x, rw(hp + 3), (hp + 3) & 1, lane, A3, B3, x3);
            select_store(A0, B0, x0, &ms[wv][hp >> 1][0], &xs[wv][hp >> 1][0],
                         hp & 1, lane);
            // step 1: work slot1, prefetch hp+4 -> slot0
            if (hp + 4 < 16)
                issue_half(neigh, x, rw(hp + 4), (hp + 4) & 1, lane, A0, B0, x0);
            select_store(A1, B1, x1, &ms[wv][(hp + 1) >> 1][0], &xs[wv][(hp + 1) >> 1][0],
                         (hp + 1) & 1, lane);
            // step 2: work slot2, prefetch hp+5 -> slot1
            if (hp + 5 < 16)
                issue_half(neigh, x, rw(hp + 5), (hp + 5) & 1, lane, A1, B1, x1);
            select_store(A2, B2, x2, &ms[wv][(hp + 2) >> 1][0], &xs[wv][(hp + 2) >> 1][0],
                         (hp + 2) & 1, lane);
            // step 3: work slot3, prefetch hp+6 -> slot2
            if (hp + 6 < 16)
                issue_half(neigh, x, rw(hp + 6), (hp + 6) & 1, lane, A2, B2, x2);
            select_store(A3, B3, x3, &ms[wv][(hp + 3) >> 1][0], &xs[wv][(hp + 3) >> 1][0],
                         (hp + 3) & 1, lane);
        }
    }

    // drain this wave's LDS writes only (NOT vmcnt, NOT a barrier)
    asm volatile("s_waitcnt lgkmcnt(0)" ::: "memory");

    // ---------- Phase B: GEMM for this wave's 8 rows ----------
    // lane -> 4 output cols; lanes 0..31 self-half, 32..63 neigh-half
    const bool self_half = (lane < 32);
    const float* __restrict__ W = self_half ? Ks : Kn;
    const int wcol = (lane * 4) & 127;
    const float* lin = self_half ? &xs[wv][0][0] : &ms[wv][0][0];

    f32x4 acc[8];
#pragma unroll
    for (int r = 0; r < 8; ++r) acc[r] = f32x4{0.f, 0.f, 0.f, 0.f};

#pragma unroll 4
    for (int k4 = 0; k4 < 32; ++k4) {
        f32x4 wv4[4];
#pragma unroll
        for (int dk = 0; dk < 4; ++dk)
            wv4[dk] = *(const f32x4*)&W[(k4 * 4 + dk) * 128 + wcol];

        f32x4 xr[8];
#pragma unroll
        for (int r = 0; r < 8; ++r)
            xr[r] = *(const f32x4*)&lin[r * F + k4 * 4];   // wave-broadcast LDS read

#pragma unroll
        for (int r = 0; r < 8; ++r) {
#pragma unroll
            for (int dk = 0; dk < 4; ++dk) {
                const float s = xr[r][dk];
                acc[r].x = fmaf(s, wv4[dk].x, acc[r].x);
                acc[r].y = fmaf(s, wv4[dk].y, acc[r].y);
                acc[r].z = fmaf(s, wv4[dk].z, acc[r].z);
                acc[r].w = fmaf(s, wv4[dk].w, acc[r].w);
            }
        }
    }

    const f32x4 bv = *(const f32x4*)&bias[lane * 4];
#pragma unroll
    for (int r = 0; r < 8; ++r) {
        int row = row0 + r;
        if (row > rmax) row = rmax;   // duplicate store of identical values; benign
        f32x4 o;
        o.x = fmaxf(acc[r].x + bv.x, 0.f);
        o.y = fmaxf(acc[r].y + bv.y, 0.f);
        o.z = fmaxf(acc[r].z + bv.z, 0.f);
        o.w = fmaxf(acc[r].w + bv.w, 0.f);
        __builtin_nontemporal_store(o, (f32x4*)&out[(size_t)row * 256 + lane * 4]);
    }
}

} // namespace

extern "C" void kernel_launch(void* const* d_in, const int* in_sizes, int n_in,
                              void* d_out, int out_size, void* d_ws, size_t ws_size,
                              hipStream_t stream) {
    const float* x     = (const float*)d_in[0];
    const float* neigh = (const float*)d_in[1];
    const float* Ks    = (const float*)d_in[2];
    const float* Kn    = (const float*)d_in[3];
    const float* bias  = (const float*)d_in[4];
    float* out = (float*)d_out;

    const int N = in_sizes[0] / F;   // 50000
    const int grid = (N + BR - 1) / BR;
    hipLaunchKernelGGL(fused_median_gemm, dim3(grid), dim3(TPB), 0, stream,
                       x, neigh, Ks, Kn, bias, out, N);
}